// Round 4
// baseline (1881.551 us; speedup 1.0000x reference)
//
#include <hip/hip_runtime.h>
#include <cstdint>
#include <climits>
#include <math.h>

#define NN 50000
#define EE 1600000
#define ET (EE + NN)   // real edges + one self-loop per node
#define GG 512
#define NEG_SLOPE 0.2f
#define NB 196          // ceil(NN/256) scan blocks

typedef _Float16 half2v __attribute__((ext_vector_type(2)));

__device__ __forceinline__ uint32_t packh2(float a, float b) {
    union { half2v h; uint32_t u; } c;
    c.h = half2v{(_Float16)a, (_Float16)b};
    return c.u;
}
__device__ __forceinline__ float2 uph(uint32_t u) {
    union { uint32_t u; half2v h; } c;
    c.u = u;
    return make_float2((float)c.h.x, (float)c.h.y);
}
__device__ __forceinline__ uint32_t pkadd(uint32_t a, uint32_t b) {
    union { uint32_t u; half2v h; } x, y, z;
    x.u = a; y.u = b;
    z.h = x.h + y.h;    // v_pk_add_f16
    return z.u;
}
__device__ __forceinline__ float fdot2u(uint32_t a, uint32_t b, float c) {
    union { uint32_t u; half2v h; } ua, ub;
    ua.u = a; ub.u = b;
    return __builtin_amdgcn_fdot2(ua.h, ub.h, c, false);
}
__device__ __forceinline__ float rlanef(float v, int l) {
    return __int_as_float(__builtin_amdgcn_readlane(__float_as_int(v), l));
}

// ---------- degree histogram ----------
__global__ void k_hist(const int* __restrict__ dst, int* __restrict__ hist) {
    int e = blockIdx.x * blockDim.x + threadIdx.x;
    if (e < EE) atomicAdd(&hist[dst[e]], 1);
}

// ---------- CSR build ----------
__global__ void k_scan_a(const int* __restrict__ hist, int* __restrict__ bsum) {
    __shared__ int tmp[256];
    int i = blockIdx.x * 256 + threadIdx.x;
    tmp[threadIdx.x] = (i < NN) ? hist[i] : 0;
    __syncthreads();
    for (int d = 128; d; d >>= 1) {
        if (threadIdx.x < d) tmp[threadIdx.x] += tmp[threadIdx.x + d];
        __syncthreads();
    }
    if (threadIdx.x == 0) bsum[blockIdx.x] = tmp[0];
}

__global__ void k_scan_b(int* __restrict__ bsum, int* __restrict__ rowptr) {
    __shared__ int tmp[256];
    int t = threadIdx.x;
    int v = (t < NB) ? bsum[t] : 0;
    tmp[t] = v;
    __syncthreads();
    for (int d = 1; d < 256; d <<= 1) {
        int u = (t >= d) ? tmp[t - d] : 0;
        __syncthreads();
        tmp[t] += u;
        __syncthreads();
    }
    if (t < NB) bsum[t] = tmp[t] - v;        // exclusive
    if (t == 255) rowptr[NN] = tmp[255];     // total == EE
}

// rowptr + cursor init fused
__global__ void k_scan_c(const int* __restrict__ hist, const int* __restrict__ bsum,
                         int* __restrict__ rowptr, int* __restrict__ cursor) {
    __shared__ int tmp[256];
    int i = blockIdx.x * 256 + threadIdx.x;
    int v = (i < NN) ? hist[i] : 0;
    tmp[threadIdx.x] = v;
    __syncthreads();
    for (int d = 1; d < 256; d <<= 1) {
        int t = (threadIdx.x >= d) ? tmp[threadIdx.x - d] : 0;
        __syncthreads();
        tmp[threadIdx.x] += t;
        __syncthreads();
    }
    if (i < NN) {
        int rp = tmp[threadIdx.x] - v + bsum[blockIdx.x];
        rowptr[i] = rp;
        cursor[i] = rp;
    }
}

// ---------- scatter + csr_src/csr_dst + fp16 AoS ea pack, one pass ----------
__global__ void k_scatter(const int* __restrict__ srcv, const int* __restrict__ dstv,
                          const float* __restrict__ ea, int* __restrict__ cursor,
                          int* __restrict__ csr_src, int* __restrict__ csr_dst,
                          uint32_t* __restrict__ eaa) {
    int e = blockIdx.x * blockDim.x + threadIdx.x;
    if (e >= EE) return;
    int d = dstv[e];
    int p = atomicAdd(&cursor[d], 1);
    csr_src[p] = srcv[e];
    csr_dst[p] = d;
    const float* r = ea + (size_t)e * 18;
    uint32_t o[12];
#pragma unroll
    for (int kk = 0; kk < 9; kk++) {
        float2 q = *(const float2*)(r + 2 * kk);
        o[kk] = packh2(q.x, q.y);
    }
    o[9] = o[10] = o[11] = 0;
    uint4* dst = (uint4*)(eaa + (size_t)p * 12);
    dst[0] = *(uint4*)&o[0];
    dst[1] = *(uint4*)&o[4];
    dst[2] = *(uint4*)&o[8];
}

// ---------- self-loop edge attr = mean of incoming ea; append virtual edges ----------
__global__ void __launch_bounds__(256)
k_loop2(const int* __restrict__ rowptr, uint32_t* __restrict__ eaa,
        int* __restrict__ csr_src, int* __restrict__ csr_dst) {
    const int lane = threadIdx.x & 63;
    int wid = blockIdx.x * (blockDim.x >> 6) + (threadIdx.x >> 6);
    int nw = gridDim.x * (blockDim.x >> 6);

    for (int i = wid; i < NN; i += nw) {
        int beg = __builtin_amdgcn_readfirstlane(rowptr[i]);
        int end = __builtin_amdgcn_readfirstlane(rowptr[i + 1]);
        float s[18];
#pragma unroll
        for (int j = 0; j < 18; j++) s[j] = 0.f;
        for (int cs = beg; cs < end; cs += 64) {
            int cnt = end - cs; if (cnt > 64) cnt = 64;
            if (lane < cnt) {
                const uint32_t* pe = eaa + (size_t)(cs + lane) * 12;
                uint4 a = *(const uint4*)pe;
                uint4 b = *(const uint4*)(pe + 4);
                uint32_t c = pe[8];
                uint32_t w[9] = {a.x, a.y, a.z, a.w, b.x, b.y, b.z, b.w, c};
#pragma unroll
                for (int kk = 0; kk < 9; kk++) {
                    float2 q = uph(w[kk]);
                    s[2 * kk] += q.x; s[2 * kk + 1] += q.y;
                }
            }
        }
#pragma unroll
        for (int j = 0; j < 18; j++) {
#pragma unroll
            for (int off = 32; off; off >>= 1) s[j] += __shfl_xor(s[j], off, 64);
        }
        if (lane == 0) {
            int deg = end - beg;
            float rd = (deg > 0) ? 1.0f / (float)deg : 0.0f;
            uint32_t o[12];
#pragma unroll
            for (int kk = 0; kk < 9; kk++) o[kk] = packh2(s[2 * kk] * rd, s[2 * kk + 1] * rd);
            o[9] = o[10] = o[11] = 0;
            uint4* dst = (uint4*)(eaa + (size_t)(EE + i) * 12);
            dst[0] = *(uint4*)&o[0];
            dst[1] = *(uint4*)&o[4];
            dst[2] = *(uint4*)&o[8];
            csr_src[EE + i] = i; csr_dst[EE + i] = i;
        }
    }
}

// ---------- pack WeT (zero-padded to CP cols): per col: 9 fp16-pair dwords + att ----------
__global__ void k_pack_wet(const float* __restrict__ We, const float* __restrict__ att,
                           uint32_t* __restrict__ WeT, int C, int CP) {
    int t = blockIdx.x * blockDim.x + threadIdx.x;
    if (t >= CP * 10) return;
    int c = t / 10, kk = t - c * 10;
    int g = c >> 2, j = c & 3;
    uint32_t v = 0;
    if (c < C) {
        if (kk < 9) v = packh2(We[(2 * kk) * C + c], We[(2 * kk + 1) * C + c]);
        else v = __float_as_uint(att[c]);
    }
    WeT[g * 40 + j * 10 + kk] = v;
}

// ---------- combine Wl|Wr into padded Wc [K x NP], biases into bc [NP] ----------
__global__ void k_combine_w(const float* __restrict__ Wl, const float* __restrict__ bl,
                            const float* __restrict__ Wr, const float* __restrict__ br,
                            float* __restrict__ Wc, float* __restrict__ bc,
                            int K, int C, int NP) {
    int t = blockIdx.x * blockDim.x + threadIdx.x;
    if (t < K * NP) {
        int k = t / NP, n = t - k * NP;
        float v = 0.0f;
        if (n < C) v = Wl[k * C + n];
        else if (n < 2 * C) v = Wr[k * C + n - C];
        Wc[t] = v;
    }
    if (t < NP) {
        float v = 0.0f;
        if (t < C) v = bl[t];
        else if (t < 2 * C) v = br[t - C];
        bc[t] = v;
    }
}

// ---------- tiled dual GEMM -> xl16/xr16 (packed fp16 only, padded pitch RL) ----------
template <int KK, int NP, int C, int RL>
__global__ void __launch_bounds__(256)
k_gemm_dual(const float* __restrict__ A, const float* __restrict__ Wc,
            const float* __restrict__ bc,
            uint32_t* __restrict__ xl16, uint32_t* __restrict__ xr16) {
    constexpr int BM = 64, BN = 64, BK = 16;
    __shared__ float As[BK][BM];
    __shared__ float Ws[BK][BN];
    const int tidx = threadIdx.x;
    const int tx = tidx & 15;
    const int ty = tidx >> 4;
    const int m0 = blockIdx.x * BM;
    const int n0 = blockIdx.y * BN;

    float acc[4][4];
#pragma unroll
    for (int i2 = 0; i2 < 4; i2++)
#pragma unroll
        for (int j2 = 0; j2 < 4; j2++) acc[i2][j2] = 0.0f;

    for (int k0 = 0; k0 < KK; k0 += BK) {
        {
            int m = tidx >> 2;
            int kq = (tidx & 3) * 4;
            float4 v = make_float4(0.f, 0.f, 0.f, 0.f);
            if (m0 + m < NN && k0 + kq < KK)
                v = *(const float4*)(A + (size_t)(m0 + m) * KK + k0 + kq);
            As[kq + 0][m] = v.x; As[kq + 1][m] = v.y;
            As[kq + 2][m] = v.z; As[kq + 3][m] = v.w;
        }
        {
            int k = tidx >> 4;
            int nq = (tidx & 15) * 4;
            float4 v = make_float4(0.f, 0.f, 0.f, 0.f);
            if (k0 + k < KK)
                v = *(const float4*)(Wc + (size_t)(k0 + k) * NP + n0 + nq);
            *(float4*)&Ws[k][nq] = v;
        }
        __syncthreads();
#pragma unroll
        for (int k = 0; k < BK; k++) {
            float a[4], b[4];
            *(float4*)a = *(const float4*)&As[k][ty * 4];
            *(float4*)b = *(const float4*)&Ws[k][tx * 4];
#pragma unroll
            for (int i2 = 0; i2 < 4; i2++)
#pragma unroll
                for (int j2 = 0; j2 < 4; j2++) acc[i2][j2] += a[i2] * b[j2];
        }
        __syncthreads();
    }

    const int n = n0 + tx * 4;
    float4 bcv = *(const float4*)(bc + n);
#pragma unroll
    for (int i2 = 0; i2 < 4; i2++) {
        int m = m0 + ty * 4 + i2;
        if (m >= NN) continue;
        float4 o = make_float4(acc[i2][0] + bcv.x, acc[i2][1] + bcv.y,
                               acc[i2][2] + bcv.z, acc[i2][3] + bcv.w);
        uint2 p;
        p.x = packh2(o.x, o.y);
        p.y = packh2(o.z, o.w);
        if (n < C)          *(uint2*)(xl16 + (size_t)m * RL + n / 2) = p;
        else if (n < 2 * C) *(uint2*)(xr16 + (size_t)m * RL + (n - C) / 2) = p;
    }
}

// ---------- score compute helper: 4 cols from 2 packed dwords ----------
__device__ __forceinline__ void grp4(const uint32_t* __restrict__ wg,
                                     const uint32_t* __restrict__ e9,
                                     uint32_t ud0, uint32_t ud1, float& score) {
    float2 f0 = uph(ud0), f1 = uph(ud1);
    float cv[4] = {f0.x, f0.y, f1.x, f1.y};
#pragma unroll
    for (int j = 0; j < 4; j++) {
        float w = 0.0f;
#pragma unroll
        for (int kk = 0; kk < 9; kk++) w = fdot2u(e9[kk], wg[j * 10 + kk], w);
        float u = cv[j] + w;
        float h = fmaxf(u, NEG_SLOPE * u);
        score = fmaf(__uint_as_float(wg[j * 10 + 9]), h, score);
    }
}

// ---------- edge-parallel scores: 2 edges/thread, chunked double-buffered loads ----------
template <int C, int CP>
__global__ void __launch_bounds__(256, 4)
k_score(const int* __restrict__ csr_src, const int* __restrict__ csr_dst,
        const uint32_t* __restrict__ eaa, const uint32_t* __restrict__ WeT,
        const uint32_t* __restrict__ xl16, const uint32_t* __restrict__ xr16,
        float* __restrict__ scores) {
    constexpr int RL = CP / 2;     // row pitch in dwords
    constexpr int NCH = CP / 8;    // chunks of 4 dwords (8 cols)
    int t = blockIdx.x * blockDim.x + threadIdx.x;
    int p0 = 2 * t;
    if (p0 >= ET) return;
    int p1 = p0 + 1;
    const bool v1 = p1 < ET;
    int s0 = csr_src[p0], d0 = csr_dst[p0];
    int s1 = v1 ? csr_src[p1] : s0, d1 = v1 ? csr_dst[p1] : d0;

    const uint4* plA = (const uint4*)(xl16 + (size_t)s0 * RL);
    const uint4* prA = (const uint4*)(xr16 + (size_t)d0 * RL);
    const uint4* plB = (const uint4*)(xl16 + (size_t)s1 * RL);
    const uint4* prB = (const uint4*)(xr16 + (size_t)d1 * RL);

    uint4 lA = plA[0], rA = prA[0], lB = plB[0], rB = prB[0];

    const uint32_t* peA = eaa + (size_t)p0 * 12;
    const uint32_t* peB = eaa + (size_t)(v1 ? p1 : p0) * 12;
    uint4 a0 = *(const uint4*)peA; uint4 a1 = *(const uint4*)(peA + 4);
    uint4 b0 = *(const uint4*)peB; uint4 b1 = *(const uint4*)(peB + 4);
    uint32_t eA[9] = {a0.x, a0.y, a0.z, a0.w, a1.x, a1.y, a1.z, a1.w, peA[8]};
    uint32_t eB[9] = {b0.x, b0.y, b0.z, b0.w, b1.x, b1.y, b1.z, b1.w, peB[8]};

    float sA = 0.0f, sB = 0.0f;
#pragma unroll 2
    for (int ch = 0; ch < NCH; ch++) {
        uint4 lA2, rA2, lB2, rB2;
        if (ch + 1 < NCH) {
            lA2 = plA[ch + 1]; rA2 = prA[ch + 1];
            lB2 = plB[ch + 1]; rB2 = prB[ch + 1];
        }
        const uint32_t* wg0 = WeT + (2 * ch) * 40;       // wave-uniform
        const uint32_t* wg1 = wg0 + 40;
        {
            uint32_t c0 = pkadd(lA.x, rA.x), c1 = pkadd(lA.y, rA.y);
            uint32_t c2 = pkadd(lA.z, rA.z), c3 = pkadd(lA.w, rA.w);
            grp4(wg0, eA, c0, c1, sA);
            grp4(wg1, eA, c2, c3, sA);
        }
        {
            uint32_t c0 = pkadd(lB.x, rB.x), c1 = pkadd(lB.y, rB.y);
            uint32_t c2 = pkadd(lB.z, rB.z), c3 = pkadd(lB.w, rB.w);
            grp4(wg0, eB, c0, c1, sB);
            grp4(wg1, eB, c2, c3, sB);
        }
        if (ch + 1 < NCH) { lA = lA2; rA = rA2; lB = lB2; rB = rB2; }
    }
    scores[p0] = sA;
    if (v1) scores[p1] = sB;
}

// ---------- per-node exact softmax + aggregation from fp16 rows (wave per node) -----
template <int C, int VEC, int RELU>
__global__ void __launch_bounds__(256)
k_fin(const int* __restrict__ rowptr, const int* __restrict__ csr_src,
      const float* __restrict__ scores, const uint32_t* __restrict__ xl16,
      const float* __restrict__ bias, float* __restrict__ out) {
    constexpr int DW = VEC / 2;              // dwords per lane per row
    constexpr int RL = ((C / 2) + 3) & ~3;   // row pitch in dwords
    constexpr int NL = C / VEC;
    const int lane = threadIdx.x & 63;
    int wid = blockIdx.x * (blockDim.x >> 6) + (threadIdx.x >> 6);
    int nw = gridDim.x * (blockDim.x >> 6);
    const bool act = lane < NL;

    float bv[VEC];
    if (act) {
#pragma unroll
        for (int j = 0; j < VEC; j++) bv[j] = bias[lane * VEC + j];
    } else {
#pragma unroll
        for (int j = 0; j < VEC; j++) bv[j] = 0.f;
    }

    auto ldrow = [&](uint32_t (&buf)[DW], int node) {
        if (act) {
            if constexpr (DW == 2) {
                uint2 v = *(const uint2*)(xl16 + (size_t)node * RL + lane * 2);
                buf[0] = v.x; buf[1] = v.y;
            } else {
                buf[0] = xl16[(size_t)node * RL + lane];
            }
        } else {
#pragma unroll
            for (int q = 0; q < DW; q++) buf[q] = 0;
        }
    };

    for (int i = wid; i < NN; i += nw) {
        int beg = __builtin_amdgcn_readfirstlane(rowptr[i]);
        int end = __builtin_amdgcn_readfirstlane(rowptr[i + 1]);
        float s_self = scores[EE + i];

        // pass 1: exact max
        float m = s_self;
        for (int cs = beg; cs < end; cs += 64) {
            int cnt = end - cs; if (cnt > 64) cnt = 64;
            float sc = (lane < cnt) ? scores[cs + lane] : -INFINITY;
#pragma unroll
            for (int off = 32; off; off >>= 1) sc = fmaxf(sc, __shfl_xor(sc, off, 64));
            m = fmaxf(m, sc);
        }

        // self-loop contribution
        float acc[VEC];
        float pes = __expf(s_self - m);
        float z = pes;
        {
            uint32_t w[DW];
            ldrow(w, i);
#pragma unroll
            for (int q = 0; q < DW; q++) {
                float2 f = uph(w[q]);
                acc[2 * q] = pes * f.x;
                acc[2 * q + 1] = pes * f.y;
            }
        }

        // pass 2: exp + denom + aggregation (rotating 4-buffer, 12-edge prefetch)
        for (int cs = beg; cs < end; cs += 64) {
            int cnt = end - cs; if (cnt > 64) cnt = 64;
            float sc = (lane < cnt) ? scores[cs + lane] : -INFINITY;
            int srcl = (lane < cnt) ? csr_src[cs + lane] : 0;
            float pe = __expf(sc - m);
            float zc = pe;
#pragma unroll
            for (int off = 32; off; off >>= 1) zc += __shfl_xor(zc, off, 64);
            z += zc;

            uint32_t bA[4][DW], bB[4][DW], bC[4][DW], bD[4][DW];
            auto LD4 = [&](uint32_t (&buf)[4][DW], int t0) {
#pragma unroll
                for (int q = 0; q < 4; q++) {
                    int tt = t0 + q;
                    if (tt < cnt) {
                        int sx = __builtin_amdgcn_readlane(srcl, tt);
                        ldrow(buf[q], sx);
                    }
                }
            };
            auto USE4 = [&](uint32_t (&buf)[4][DW], int t0) {
#pragma unroll
                for (int q = 0; q < 4; q++) {
                    int tt = t0 + q;
                    if (tt < cnt) {
                        float a = rlanef(pe, tt);
#pragma unroll
                        for (int qq = 0; qq < DW; qq++) {
                            float2 f = uph(buf[q][qq]);
                            acc[2 * qq] = fmaf(a, f.x, acc[2 * qq]);
                            acc[2 * qq + 1] = fmaf(a, f.y, acc[2 * qq + 1]);
                        }
                    }
                }
            };
            LD4(bA, 0); LD4(bB, 4); LD4(bC, 8);
            USE4(bA, 0);  LD4(bD, 12);
            USE4(bB, 4);  LD4(bA, 16);
            USE4(bC, 8);  LD4(bB, 20);
            USE4(bD, 12); LD4(bC, 24);
            USE4(bA, 16); LD4(bD, 28);
            USE4(bB, 20); LD4(bA, 32);
            USE4(bC, 24); LD4(bB, 36);
            USE4(bD, 28); LD4(bC, 40);
            USE4(bA, 32); LD4(bD, 44);
            USE4(bB, 36); LD4(bA, 48);
            USE4(bC, 40); LD4(bB, 52);
            USE4(bD, 44); LD4(bC, 56);
            USE4(bA, 48); LD4(bD, 60);
            USE4(bB, 52);
            USE4(bC, 56);
            USE4(bD, 60);
        }

        float rz = 1.0f / z;
        if (act) {
            float o[VEC];
#pragma unroll
            for (int j = 0; j < VEC; j++) {
                o[j] = acc[j] * rz + bv[j];
                if (RELU) o[j] = fmaxf(o[j], 0.0f);
            }
            if constexpr (VEC == 4) {
                *(float4*)(out + (size_t)i * C + lane * 4) = make_float4(o[0], o[1], o[2], o[3]);
            } else {
                *(float2*)(out + (size_t)i * C + lane * 2) = make_float2(o[0], o[1]);
            }
        }
    }
}

// ---------- mean pooling per graph (batch_ids sorted); relu folded in ----------
__global__ void k_pool(const float* __restrict__ h, const int* __restrict__ batch,
                       float* __restrict__ pooled) {
    int g = blockIdx.x;
    int lo = 0, hi = NN;
    while (lo < hi) { int mid = (lo + hi) >> 1; if (batch[mid] < g) lo = mid + 1; else hi = mid; }
    int start = lo;
    lo = start; hi = NN;
    while (lo < hi) { int mid = (lo + hi) >> 1; if (batch[mid] < g + 1) lo = mid + 1; else hi = mid; }
    int end = lo;
    float cnt = (float)(end - start);
    int c = threadIdx.x;
    if (c < 200) {
        float acc = 0.0f;
        for (int i = start; i < end; i++) acc += fmaxf(h[(size_t)i * 200 + c], 0.0f);
        pooled[g * 200 + c] = acc / fmaxf(cnt, 1.0f);
    }
}

// ---------- small dense layers on [G, *] ----------
__global__ void k_mlp(const float* __restrict__ X, const float* __restrict__ W,
                      const float* __restrict__ b, float* __restrict__ Y,
                      int Cin, int Cout, int do_relu) {
    int t = blockIdx.x * blockDim.x + threadIdx.x;
    if (t >= GG * Cout) return;
    int g = t / Cout, j = t - g * Cout;
    const float* xrow = X + (size_t)g * Cin;
    float acc = b[j];
    for (int k = 0; k < Cin; k++) acc += xrow[k] * W[k * Cout + j];
    if (do_relu) acc = fmaxf(acc, 0.0f);
    Y[t] = acc;
}

extern "C" void kernel_launch(void* const* d_in, const int* in_sizes, int n_in,
                              void* d_out, int out_size, void* d_ws, size_t ws_size,
                              hipStream_t stream) {
    const float* x   = (const float*)d_in[0];
    const int*   ei  = (const int*)d_in[1];
    const float* ea  = (const float*)d_in[2];
    const int*   bat = (const int*)d_in[3];
    const float* W1l = (const float*)d_in[4];  const float* b1l = (const float*)d_in[5];
    const float* W1r = (const float*)d_in[6];  const float* b1r = (const float*)d_in[7];
    const float* W1e = (const float*)d_in[8];
    const float* a1  = (const float*)d_in[9];  const float* c1  = (const float*)d_in[10];
    const float* W2l = (const float*)d_in[11]; const float* b2l = (const float*)d_in[12];
    const float* W2r = (const float*)d_in[13]; const float* b2r = (const float*)d_in[14];
    const float* W2e = (const float*)d_in[15];
    const float* a2  = (const float*)d_in[16]; const float* c2  = (const float*)d_in[17];
    const float* W3  = (const float*)d_in[18]; const float* b3  = (const float*)d_in[19];
    const float* F1  = (const float*)d_in[20]; const float* bf1 = (const float*)d_in[21];
    const float* F2  = (const float*)d_in[22]; const float* bf2 = (const float*)d_in[23];
    const float* F3  = (const float*)d_in[24]; const float* bf3 = (const float*)d_in[25];

    const int* srcv = ei;        // edge_index[0]
    const int* dstv = ei + EE;   // edge_index[1]

    float* W = (float*)d_ws;
    size_t off = 0;
    int*      hist    = (int*)(W + off); off += NN;
    float*    h1      = W + off; off += (size_t)NN * 100;
    float*    h2      = W + off; off += (size_t)NN * 200;
    int*      rowptr  = (int*)(W + off); off += NN + 4;
    int*      cursor  = (int*)(W + off); off += NN;
    int*      bsum    = (int*)(W + off); off += 256;
    float*    scores  = W + off; off += ET;
    int*      csr_src = (int*)(W + off); off += ET;
    int*      csr_dst = (int*)(W + off); off += ET;
    uint32_t* eaa     = (uint32_t*)(W + off); off += (size_t)ET * 12;
    uint32_t* xl16    = (uint32_t*)(W + off); off += (size_t)NN * 100;
    uint32_t* xr16    = (uint32_t*)(W + off); off += (size_t)NN * 100;
    uint32_t* WeT1    = (uint32_t*)(W + off); off += 26 * 40;
    uint32_t* WeT2    = (uint32_t*)(W + off); off += 50 * 40;
    float*    Wc1     = W + off; off += 16 * 256;
    float*    bc1     = W + off; off += 256;
    float*    Wc2     = W + off; off += 100 * 448;
    float*    bc2     = W + off; off += 448;
    float*    pooled  = W + off; off += (size_t)GG * 200;
    float*    p400    = W + off; off += (size_t)GG * 400;
    float*    y1      = W + off; off += (size_t)GG * 200;
    float*    y2      = W + off; off += (size_t)GG * 100;
    (void)ws_size; (void)n_in; (void)in_sizes; (void)out_size;

    const int B = 256;
    const int NODEB = 12500;   // 4 waves/block -> 50000 waves, 1 node each

    // ---- degree histogram + CSR by dst; scatter also packs ea + src/dst ----
    hipMemsetAsync(hist, 0, (size_t)NN * sizeof(int), stream);
    k_hist<<<(EE + B - 1) / B, B, 0, stream>>>(dstv, hist);
    k_scan_a<<<NB, 256, 0, stream>>>(hist, bsum);
    k_scan_b<<<1, 256, 0, stream>>>(bsum, rowptr);
    k_scan_c<<<NB, 256, 0, stream>>>(hist, bsum, rowptr, cursor);
    k_scatter<<<(EE + B - 1) / B, B, 0, stream>>>(srcv, dstv, ea, cursor, csr_src, csr_dst, eaa);
    k_loop2<<<NODEB, B, 0, stream>>>(rowptr, eaa, csr_src, csr_dst);

    // ---- weight prep ----
    k_pack_wet<<<(104 * 10 + B - 1) / B, B, 0, stream>>>(W1e, a1, WeT1, 100, 104);
    k_pack_wet<<<(200 * 10 + B - 1) / B, B, 0, stream>>>(W2e, a2, WeT2, 200, 200);
    k_combine_w<<<(16 * 256 + B - 1) / B, B, 0, stream>>>(W1l, b1l, W1r, b1r, Wc1, bc1, 16, 100, 256);
    k_combine_w<<<(100 * 448 + B - 1) / B, B, 0, stream>>>(W2l, b2l, W2r, b2r, Wc2, bc2, 100, 200, 448);

    // ---- GAT layer 1: 16 -> 100 (RL = 52; pads must be zero for padded score cols) ----
    hipMemsetAsync(xl16, 0, (size_t)NN * 52 * 4, stream);
    hipMemsetAsync(xr16, 0, (size_t)NN * 52 * 4, stream);
    {
        dim3 grid((NN + 63) / 64, 256 / 64);
        k_gemm_dual<16, 256, 100, 52><<<grid, 256, 0, stream>>>(x, Wc1, bc1, xl16, xr16);
    }
    k_score<100, 104><<<(ET / 2 + B - 1) / B, B, 0, stream>>>(csr_src, csr_dst, eaa, WeT1, xl16, xr16, scores);
    k_fin<100, 2, 1><<<NODEB, B, 0, stream>>>(rowptr, csr_src, scores, xl16, c1, h1);

    // ---- GAT layer 2: 100 -> 200 (RL = 100) ----
    {
        dim3 grid((NN + 63) / 64, 448 / 64);
        k_gemm_dual<100, 448, 200, 100><<<grid, 256, 0, stream>>>(h1, Wc2, bc2, xl16, xr16);
    }
    k_score<200, 200><<<(ET / 2 + B - 1) / B, B, 0, stream>>>(csr_src, csr_dst, eaa, WeT2, xl16, xr16, scores);
    k_fin<200, 4, 0><<<NODEB, B, 0, stream>>>(rowptr, csr_src, scores, xl16, c2, h2);

    // ---- pool (mean over graph, relu fused) then W3 + FFN ----
    k_pool<<<GG, 256, 0, stream>>>(h2, bat, pooled);
    k_mlp<<<(GG * 400 + B - 1) / B, B, 0, stream>>>(pooled, W3, b3, p400, 200, 400, 0);
    k_mlp<<<(GG * 200 + B - 1) / B, B, 0, stream>>>(p400, F1, bf1, y1, 400, 200, 1);
    k_mlp<<<(GG * 100 + B - 1) / B, B, 0, stream>>>(y1, F2, bf2, y2, 200, 100, 1);
    k_mlp<<<(GG * 100 + B - 1) / B, B, 0, stream>>>(y2, F3, bf3, (float*)d_out, 100, 100, 0);
}

// Round 5
// 1650.874 us; speedup vs baseline: 1.1397x; 1.1397x over previous
//
#include <hip/hip_runtime.h>
#include <cstdint>
#include <climits>
#include <math.h>

#define NN 50000
#define EE 1600000
#define ET (EE + NN)   // real edges + one self-loop per node
#define GG 512
#define NEG_SLOPE 0.2f
#define NB 196          // ceil(NN/256) scan blocks

typedef _Float16 half2v __attribute__((ext_vector_type(2)));

__device__ __forceinline__ uint32_t packh2(float a, float b) {
    union { half2v h; uint32_t u; } c;
    c.h = half2v{(_Float16)a, (_Float16)b};
    return c.u;
}
__device__ __forceinline__ float2 uph(uint32_t u) {
    union { uint32_t u; half2v h; } c;
    c.u = u;
    return make_float2((float)c.h.x, (float)c.h.y);
}
__device__ __forceinline__ uint32_t pkadd(uint32_t a, uint32_t b) {
    union { uint32_t u; half2v h; } x, y, z;
    x.u = a; y.u = b;
    z.h = x.h + y.h;    // v_pk_add_f16
    return z.u;
}
__device__ __forceinline__ float fdot2u(uint32_t a, uint32_t b, float c) {
    union { uint32_t u; half2v h; } ua, ub;
    ua.u = a; ub.u = b;
    return __builtin_amdgcn_fdot2(ua.h, ub.h, c, false);
}
__device__ __forceinline__ float rlanef(float v, int l) {
    return __int_as_float(__builtin_amdgcn_readlane(__float_as_int(v), l));
}

// ---------- degree histogram ----------
__global__ void k_hist(const int* __restrict__ dst, int* __restrict__ hist) {
    int e = blockIdx.x * blockDim.x + threadIdx.x;
    if (e < EE) atomicAdd(&hist[dst[e]], 1);
}

// ---------- CSR build ----------
__global__ void k_scan_a(const int* __restrict__ hist, int* __restrict__ bsum) {
    __shared__ int tmp[256];
    int i = blockIdx.x * 256 + threadIdx.x;
    tmp[threadIdx.x] = (i < NN) ? hist[i] : 0;
    __syncthreads();
    for (int d = 128; d; d >>= 1) {
        if (threadIdx.x < d) tmp[threadIdx.x] += tmp[threadIdx.x + d];
        __syncthreads();
    }
    if (threadIdx.x == 0) bsum[blockIdx.x] = tmp[0];
}

__global__ void k_scan_b(int* __restrict__ bsum, int* __restrict__ rowptr) {
    __shared__ int tmp[256];
    int t = threadIdx.x;
    int v = (t < NB) ? bsum[t] : 0;
    tmp[t] = v;
    __syncthreads();
    for (int d = 1; d < 256; d <<= 1) {
        int u = (t >= d) ? tmp[t - d] : 0;
        __syncthreads();
        tmp[t] += u;
        __syncthreads();
    }
    if (t < NB) bsum[t] = tmp[t] - v;        // exclusive
    if (t == 255) rowptr[NN] = tmp[255];     // total == EE
}

// rowptr + cursor init fused
__global__ void k_scan_c(const int* __restrict__ hist, const int* __restrict__ bsum,
                         int* __restrict__ rowptr, int* __restrict__ cursor) {
    __shared__ int tmp[256];
    int i = blockIdx.x * 256 + threadIdx.x;
    int v = (i < NN) ? hist[i] : 0;
    tmp[threadIdx.x] = v;
    __syncthreads();
    for (int d = 1; d < 256; d <<= 1) {
        int t = (threadIdx.x >= d) ? tmp[threadIdx.x - d] : 0;
        __syncthreads();
        tmp[threadIdx.x] += t;
        __syncthreads();
    }
    if (i < NN) {
        int rp = tmp[threadIdx.x] - v + bsum[blockIdx.x];
        rowptr[i] = rp;
        cursor[i] = rp;
    }
}

// ---------- scatter + csr_src/csr_dst + fp16 AoS ea pack, one pass ----------
__global__ void k_scatter(const int* __restrict__ srcv, const int* __restrict__ dstv,
                          const float* __restrict__ ea, int* __restrict__ cursor,
                          int* __restrict__ csr_src, int* __restrict__ csr_dst,
                          uint32_t* __restrict__ eaa) {
    int e = blockIdx.x * blockDim.x + threadIdx.x;
    if (e >= EE) return;
    int d = dstv[e];
    int p = atomicAdd(&cursor[d], 1);
    csr_src[p] = srcv[e];
    csr_dst[p] = d;
    const float* r = ea + (size_t)e * 18;
    uint32_t o[12];
#pragma unroll
    for (int kk = 0; kk < 9; kk++) {
        float2 q = *(const float2*)(r + 2 * kk);
        o[kk] = packh2(q.x, q.y);
    }
    o[9] = o[10] = o[11] = 0;
    uint4* dst = (uint4*)(eaa + (size_t)p * 12);
    dst[0] = *(uint4*)&o[0];
    dst[1] = *(uint4*)&o[4];
    dst[2] = *(uint4*)&o[8];
}

// ---------- self-loop edge attr = mean of incoming ea; append virtual edges ----------
__global__ void __launch_bounds__(256)
k_loop2(const int* __restrict__ rowptr, uint32_t* __restrict__ eaa,
        int* __restrict__ csr_src, int* __restrict__ csr_dst) {
    const int lane = threadIdx.x & 63;
    int wid = blockIdx.x * (blockDim.x >> 6) + (threadIdx.x >> 6);
    int nw = gridDim.x * (blockDim.x >> 6);

    for (int i = wid; i < NN; i += nw) {
        int beg = __builtin_amdgcn_readfirstlane(rowptr[i]);
        int end = __builtin_amdgcn_readfirstlane(rowptr[i + 1]);
        float s[18];
#pragma unroll
        for (int j = 0; j < 18; j++) s[j] = 0.f;
        for (int cs = beg; cs < end; cs += 64) {
            int cnt = end - cs; if (cnt > 64) cnt = 64;
            if (lane < cnt) {
                const uint32_t* pe = eaa + (size_t)(cs + lane) * 12;
                uint4 a = *(const uint4*)pe;
                uint4 b = *(const uint4*)(pe + 4);
                uint32_t c = pe[8];
                uint32_t w[9] = {a.x, a.y, a.z, a.w, b.x, b.y, b.z, b.w, c};
#pragma unroll
                for (int kk = 0; kk < 9; kk++) {
                    float2 q = uph(w[kk]);
                    s[2 * kk] += q.x; s[2 * kk + 1] += q.y;
                }
            }
        }
#pragma unroll
        for (int j = 0; j < 18; j++) {
#pragma unroll
            for (int off = 32; off; off >>= 1) s[j] += __shfl_xor(s[j], off, 64);
        }
        if (lane == 0) {
            int deg = end - beg;
            float rd = (deg > 0) ? 1.0f / (float)deg : 0.0f;
            uint32_t o[12];
#pragma unroll
            for (int kk = 0; kk < 9; kk++) o[kk] = packh2(s[2 * kk] * rd, s[2 * kk + 1] * rd);
            o[9] = o[10] = o[11] = 0;
            uint4* dst = (uint4*)(eaa + (size_t)(EE + i) * 12);
            dst[0] = *(uint4*)&o[0];
            dst[1] = *(uint4*)&o[4];
            dst[2] = *(uint4*)&o[8];
            csr_src[EE + i] = i; csr_dst[EE + i] = i;
        }
    }
}

// ---------- pack WeT (zero-padded to CP cols): per col: 9 fp16-pair dwords + att ----------
__global__ void k_pack_wet(const float* __restrict__ We, const float* __restrict__ att,
                           uint32_t* __restrict__ WeT, int C, int CP) {
    int t = blockIdx.x * blockDim.x + threadIdx.x;
    if (t >= CP * 10) return;
    int c = t / 10, kk = t - c * 10;
    int g = c >> 2, j = c & 3;
    uint32_t v = 0;
    if (c < C) {
        if (kk < 9) v = packh2(We[(2 * kk) * C + c], We[(2 * kk + 1) * C + c]);
        else v = __float_as_uint(att[c]);
    }
    WeT[g * 40 + j * 10 + kk] = v;
}

// ---------- combine Wl|Wr into padded Wc [K x NP], biases into bc [NP] ----------
__global__ void k_combine_w(const float* __restrict__ Wl, const float* __restrict__ bl,
                            const float* __restrict__ Wr, const float* __restrict__ br,
                            float* __restrict__ Wc, float* __restrict__ bc,
                            int K, int C, int NP) {
    int t = blockIdx.x * blockDim.x + threadIdx.x;
    if (t < K * NP) {
        int k = t / NP, n = t - k * NP;
        float v = 0.0f;
        if (n < C) v = Wl[k * C + n];
        else if (n < 2 * C) v = Wr[k * C + n - C];
        Wc[t] = v;
    }
    if (t < NP) {
        float v = 0.0f;
        if (t < C) v = bl[t];
        else if (t < 2 * C) v = br[t - C];
        bc[t] = v;
    }
}

// ---------- tiled dual GEMM -> xl16/xr16 (packed fp16 only, padded pitch RL) ----------
template <int KK, int NP, int C, int RL>
__global__ void __launch_bounds__(256)
k_gemm_dual(const float* __restrict__ A, const float* __restrict__ Wc,
            const float* __restrict__ bc,
            uint32_t* __restrict__ xl16, uint32_t* __restrict__ xr16) {
    constexpr int BM = 64, BN = 64, BK = 16;
    __shared__ float As[BK][BM];
    __shared__ float Ws[BK][BN];
    const int tidx = threadIdx.x;
    const int tx = tidx & 15;
    const int ty = tidx >> 4;
    const int m0 = blockIdx.x * BM;
    const int n0 = blockIdx.y * BN;

    float acc[4][4];
#pragma unroll
    for (int i2 = 0; i2 < 4; i2++)
#pragma unroll
        for (int j2 = 0; j2 < 4; j2++) acc[i2][j2] = 0.0f;

    for (int k0 = 0; k0 < KK; k0 += BK) {
        {
            int m = tidx >> 2;
            int kq = (tidx & 3) * 4;
            float4 v = make_float4(0.f, 0.f, 0.f, 0.f);
            if (m0 + m < NN && k0 + kq < KK)
                v = *(const float4*)(A + (size_t)(m0 + m) * KK + k0 + kq);
            As[kq + 0][m] = v.x; As[kq + 1][m] = v.y;
            As[kq + 2][m] = v.z; As[kq + 3][m] = v.w;
        }
        {
            int k = tidx >> 4;
            int nq = (tidx & 15) * 4;
            float4 v = make_float4(0.f, 0.f, 0.f, 0.f);
            if (k0 + k < KK)
                v = *(const float4*)(Wc + (size_t)(k0 + k) * NP + n0 + nq);
            *(float4*)&Ws[k][nq] = v;
        }
        __syncthreads();
#pragma unroll
        for (int k = 0; k < BK; k++) {
            float a[4], b[4];
            *(float4*)a = *(const float4*)&As[k][ty * 4];
            *(float4*)b = *(const float4*)&Ws[k][tx * 4];
#pragma unroll
            for (int i2 = 0; i2 < 4; i2++)
#pragma unroll
                for (int j2 = 0; j2 < 4; j2++) acc[i2][j2] += a[i2] * b[j2];
        }
        __syncthreads();
    }

    const int n = n0 + tx * 4;
    float4 bcv = *(const float4*)(bc + n);
#pragma unroll
    for (int i2 = 0; i2 < 4; i2++) {
        int m = m0 + ty * 4 + i2;
        if (m >= NN) continue;
        float4 o = make_float4(acc[i2][0] + bcv.x, acc[i2][1] + bcv.y,
                               acc[i2][2] + bcv.z, acc[i2][3] + bcv.w);
        uint2 p;
        p.x = packh2(o.x, o.y);
        p.y = packh2(o.z, o.w);
        if (n < C)          *(uint2*)(xl16 + (size_t)m * RL + n / 2) = p;
        else if (n < 2 * C) *(uint2*)(xr16 + (size_t)m * RL + (n - C) / 2) = p;
    }
}

// ---------- score compute helper: 4 cols from 2 packed dwords ----------
__device__ __forceinline__ void grp4(const uint32_t* __restrict__ wg,
                                     const uint32_t* __restrict__ e9,
                                     uint32_t ud0, uint32_t ud1, float& score) {
    float2 f0 = uph(ud0), f1 = uph(ud1);
    float cv[4] = {f0.x, f0.y, f1.x, f1.y};
#pragma unroll
    for (int j = 0; j < 4; j++) {
        float w = 0.0f;
#pragma unroll
        for (int kk = 0; kk < 9; kk++) w = fdot2u(e9[kk], wg[j * 10 + kk], w);
        float u = cv[j] + w;
        float h = fmaxf(u, NEG_SLOPE * u);
        score = fmaf(__uint_as_float(wg[j * 10 + 9]), h, score);
    }
}

// ---------- edge-parallel scores: 2 edges/thread, chunked double-buffered loads ----------
template <int C, int CP>
__global__ void __launch_bounds__(256, 4)
k_score(const int* __restrict__ csr_src, const int* __restrict__ csr_dst,
        const uint32_t* __restrict__ eaa, const uint32_t* __restrict__ WeT,
        const uint32_t* __restrict__ xl16, const uint32_t* __restrict__ xr16,
        float* __restrict__ scores) {
    constexpr int RL = CP / 2;     // row pitch in dwords
    constexpr int NCH = CP / 8;    // chunks of 4 dwords (8 cols)
    int t = blockIdx.x * blockDim.x + threadIdx.x;
    int p0 = 2 * t;
    if (p0 >= ET) return;
    int p1 = p0 + 1;
    const bool v1 = p1 < ET;
    int s0 = csr_src[p0], d0 = csr_dst[p0];
    int s1 = v1 ? csr_src[p1] : s0, d1 = v1 ? csr_dst[p1] : d0;

    const uint4* plA = (const uint4*)(xl16 + (size_t)s0 * RL);
    const uint4* prA = (const uint4*)(xr16 + (size_t)d0 * RL);
    const uint4* plB = (const uint4*)(xl16 + (size_t)s1 * RL);
    const uint4* prB = (const uint4*)(xr16 + (size_t)d1 * RL);

    uint4 lA = plA[0], rA = prA[0], lB = plB[0], rB = prB[0];

    const uint32_t* peA = eaa + (size_t)p0 * 12;
    const uint32_t* peB = eaa + (size_t)(v1 ? p1 : p0) * 12;
    uint4 a0 = *(const uint4*)peA; uint4 a1 = *(const uint4*)(peA + 4);
    uint4 b0 = *(const uint4*)peB; uint4 b1 = *(const uint4*)(peB + 4);
    uint32_t eA[9] = {a0.x, a0.y, a0.z, a0.w, a1.x, a1.y, a1.z, a1.w, peA[8]};
    uint32_t eB[9] = {b0.x, b0.y, b0.z, b0.w, b1.x, b1.y, b1.z, b1.w, peB[8]};

    float sA = 0.0f, sB = 0.0f;
#pragma unroll 2
    for (int ch = 0; ch < NCH; ch++) {
        uint4 lA2, rA2, lB2, rB2;
        if (ch + 1 < NCH) {
            lA2 = plA[ch + 1]; rA2 = prA[ch + 1];
            lB2 = plB[ch + 1]; rB2 = prB[ch + 1];
        }
        const uint32_t* wg0 = WeT + (2 * ch) * 40;       // wave-uniform
        const uint32_t* wg1 = wg0 + 40;
        {
            uint32_t c0 = pkadd(lA.x, rA.x), c1 = pkadd(lA.y, rA.y);
            uint32_t c2 = pkadd(lA.z, rA.z), c3 = pkadd(lA.w, rA.w);
            grp4(wg0, eA, c0, c1, sA);
            grp4(wg1, eA, c2, c3, sA);
        }
        {
            uint32_t c0 = pkadd(lB.x, rB.x), c1 = pkadd(lB.y, rB.y);
            uint32_t c2 = pkadd(lB.z, rB.z), c3 = pkadd(lB.w, rB.w);
            grp4(wg0, eB, c0, c1, sB);
            grp4(wg1, eB, c2, c3, sB);
        }
        if (ch + 1 < NCH) { lA = lA2; rA = rA2; lB = lB2; rB = rB2; }
    }
    scores[p0] = sA;
    if (v1) scores[p1] = sB;
}

// ---------- per-node softmax + aggregation: 2 nodes per wave, dual gather chains -----
template <int C, int VEC, int RELU>
__global__ void __launch_bounds__(256)
k_fin(const int* __restrict__ rowptr, const int* __restrict__ csr_src,
      const float* __restrict__ scores, const uint32_t* __restrict__ xl16,
      const float* __restrict__ bias, float* __restrict__ out) {
    constexpr int DW = VEC / 2;              // dwords per lane per row
    constexpr int RL = ((C / 2) + 3) & ~3;   // row pitch in dwords
    constexpr int NL = C / VEC;
    const int lane = threadIdx.x & 63;
    int wid = blockIdx.x * (blockDim.x >> 6) + (threadIdx.x >> 6);
    int nw = gridDim.x * (blockDim.x >> 6);
    const bool act = lane < NL;

    float bv[VEC];
    if (act) {
#pragma unroll
        for (int j = 0; j < VEC; j++) bv[j] = bias[lane * VEC + j];
    } else {
#pragma unroll
        for (int j = 0; j < VEC; j++) bv[j] = 0.f;
    }

    auto ldrow = [&](uint32_t (&buf)[DW], int node) {
        if (act) {
            if constexpr (DW == 2) {
                uint2 v = *(const uint2*)(xl16 + (size_t)node * RL + lane * 2);
                buf[0] = v.x; buf[1] = v.y;
            } else {
                buf[0] = xl16[(size_t)node * RL + lane];
            }
        } else {
#pragma unroll
            for (int q = 0; q < DW; q++) buf[q] = 0;
        }
    };

    for (int p = wid; p < NN / 2; p += nw) {
        const int iA = 2 * p, iB = 2 * p + 1;
        int begA = __builtin_amdgcn_readfirstlane(rowptr[iA]);
        int endA = __builtin_amdgcn_readfirstlane(rowptr[iA + 1]);
        int endB = __builtin_amdgcn_readfirstlane(rowptr[iB + 1]);
        int begB = endA;   // CSR contiguity
        float sselfA = scores[EE + iA];
        float sselfB = scores[EE + iB];

        // pass 1: exact max per node
        float mA = sselfA, mB = sselfB;
        for (int cs = begA; cs < endA; cs += 64) {
            int cnt = endA - cs; if (cnt > 64) cnt = 64;
            float sc = (lane < cnt) ? scores[cs + lane] : -INFINITY;
#pragma unroll
            for (int off = 32; off; off >>= 1) sc = fmaxf(sc, __shfl_xor(sc, off, 64));
            mA = fmaxf(mA, sc);
        }
        for (int cs = begB; cs < endB; cs += 64) {
            int cnt = endB - cs; if (cnt > 64) cnt = 64;
            float sc = (lane < cnt) ? scores[cs + lane] : -INFINITY;
#pragma unroll
            for (int off = 32; off; off >>= 1) sc = fmaxf(sc, __shfl_xor(sc, off, 64));
            mB = fmaxf(mB, sc);
        }

        // self-loop contributions
        float accA[VEC], accB[VEC];
        float pesA = __expf(sselfA - mA);
        float pesB = __expf(sselfB - mB);
        float zA = pesA, zB = pesB;
        {
            uint32_t wA[DW], wB[DW];
            ldrow(wA, iA);
            ldrow(wB, iB);
#pragma unroll
            for (int q = 0; q < DW; q++) {
                float2 fA = uph(wA[q]), fB = uph(wB[q]);
                accA[2 * q] = pesA * fA.x; accA[2 * q + 1] = pesA * fA.y;
                accB[2 * q] = pesB * fB.x; accB[2 * q + 1] = pesB * fB.y;
            }
        }

        // pass 2: dual-chain aggregation, 8-deep prefetch per chain, pinned
        int csA = begA, csB = begB;
        while (csA < endA || csB < endB) {
            int cntA = (csA < endA) ? min(endA - csA, 64) : 0;
            int cntB = (csB < endB) ? min(endB - csB, 64) : 0;
            float scA = (lane < cntA) ? scores[csA + lane] : -INFINITY;
            int srA = (lane < cntA) ? csr_src[csA + lane] : 0;
            float scB = (lane < cntB) ? scores[csB + lane] : -INFINITY;
            int srB = (lane < cntB) ? csr_src[csB + lane] : 0;
            float peA = __expf(scA - mA);
            float peB = __expf(scB - mB);
            float zcA = peA, zcB = peB;
#pragma unroll
            for (int off = 32; off; off >>= 1) {
                zcA += __shfl_xor(zcA, off, 64);
                zcB += __shfl_xor(zcB, off, 64);
            }
            zA += zcA; zB += zcB;

            uint32_t A1[4][DW], A2[4][DW], B1[4][DW], B2[4][DW];
            auto LD4 = [&](uint32_t (&buf)[4][DW], int srcl, int cnt, int t0) {
#pragma unroll
                for (int q = 0; q < 4; q++) {
                    int tt = t0 + q;
                    if (tt < cnt) {
                        int sx = __builtin_amdgcn_readlane(srcl, tt);
                        ldrow(buf[q], sx);
                    }
                }
            };
            auto USE4 = [&](uint32_t (&buf)[4][DW], float pe, float (&acc)[VEC],
                            int cnt, int t0) {
#pragma unroll
                for (int q = 0; q < 4; q++) {
                    int tt = t0 + q;
                    if (tt < cnt) {
                        float a = rlanef(pe, tt);
#pragma unroll
                        for (int qq = 0; qq < DW; qq++) {
                            float2 f = uph(buf[q][qq]);
                            acc[2 * qq] = fmaf(a, f.x, acc[2 * qq]);
                            acc[2 * qq + 1] = fmaf(a, f.y, acc[2 * qq + 1]);
                        }
                    }
                }
            };

            int mx = (cntA > cntB) ? cntA : cntB;
            LD4(A1, srA, cntA, 0);
            LD4(B1, srB, cntB, 0);
            for (int t0 = 0; t0 < mx; t0 += 8) {
                LD4(A2, srA, cntA, t0 + 4);
                LD4(B2, srB, cntB, t0 + 4);
                __builtin_amdgcn_sched_barrier(0);
                USE4(A1, peA, accA, cntA, t0);
                USE4(B1, peB, accB, cntB, t0);
                LD4(A1, srA, cntA, t0 + 8);
                LD4(B1, srB, cntB, t0 + 8);
                __builtin_amdgcn_sched_barrier(0);
                USE4(A2, peA, accA, cntA, t0 + 4);
                USE4(B2, peB, accB, cntB, t0 + 4);
            }
            csA += 64; csB += 64;
        }

        if (act) {
            float rzA = 1.0f / zA, rzB = 1.0f / zB;
            float oA[VEC], oB[VEC];
#pragma unroll
            for (int j = 0; j < VEC; j++) {
                oA[j] = accA[j] * rzA + bv[j];
                oB[j] = accB[j] * rzB + bv[j];
                if (RELU) { oA[j] = fmaxf(oA[j], 0.0f); oB[j] = fmaxf(oB[j], 0.0f); }
            }
            if constexpr (VEC == 4) {
                *(float4*)(out + (size_t)iA * C + lane * 4) = make_float4(oA[0], oA[1], oA[2], oA[3]);
                *(float4*)(out + (size_t)iB * C + lane * 4) = make_float4(oB[0], oB[1], oB[2], oB[3]);
            } else {
                *(float2*)(out + (size_t)iA * C + lane * 2) = make_float2(oA[0], oA[1]);
                *(float2*)(out + (size_t)iB * C + lane * 2) = make_float2(oB[0], oB[1]);
            }
        }
    }
}

// ---------- mean pooling per graph (batch_ids sorted); relu folded in ----------
__global__ void k_pool(const float* __restrict__ h, const int* __restrict__ batch,
                       float* __restrict__ pooled) {
    int g = blockIdx.x;
    int lo = 0, hi = NN;
    while (lo < hi) { int mid = (lo + hi) >> 1; if (batch[mid] < g) lo = mid + 1; else hi = mid; }
    int start = lo;
    lo = start; hi = NN;
    while (lo < hi) { int mid = (lo + hi) >> 1; if (batch[mid] < g + 1) lo = mid + 1; else hi = mid; }
    int end = lo;
    float cnt = (float)(end - start);
    int c = threadIdx.x;
    if (c < 200) {
        float acc = 0.0f;
        for (int i = start; i < end; i++) acc += fmaxf(h[(size_t)i * 200 + c], 0.0f);
        pooled[g * 200 + c] = acc / fmaxf(cnt, 1.0f);
    }
}

// ---------- small dense layers on [G, *] ----------
__global__ void k_mlp(const float* __restrict__ X, const float* __restrict__ W,
                      const float* __restrict__ b, float* __restrict__ Y,
                      int Cin, int Cout, int do_relu) {
    int t = blockIdx.x * blockDim.x + threadIdx.x;
    if (t >= GG * Cout) return;
    int g = t / Cout, j = t - g * Cout;
    const float* xrow = X + (size_t)g * Cin;
    float acc = b[j];
    for (int k = 0; k < Cin; k++) acc += xrow[k] * W[k * Cout + j];
    if (do_relu) acc = fmaxf(acc, 0.0f);
    Y[t] = acc;
}

extern "C" void kernel_launch(void* const* d_in, const int* in_sizes, int n_in,
                              void* d_out, int out_size, void* d_ws, size_t ws_size,
                              hipStream_t stream) {
    const float* x   = (const float*)d_in[0];
    const int*   ei  = (const int*)d_in[1];
    const float* ea  = (const float*)d_in[2];
    const int*   bat = (const int*)d_in[3];
    const float* W1l = (const float*)d_in[4];  const float* b1l = (const float*)d_in[5];
    const float* W1r = (const float*)d_in[6];  const float* b1r = (const float*)d_in[7];
    const float* W1e = (const float*)d_in[8];
    const float* a1  = (const float*)d_in[9];  const float* c1  = (const float*)d_in[10];
    const float* W2l = (const float*)d_in[11]; const float* b2l = (const float*)d_in[12];
    const float* W2r = (const float*)d_in[13]; const float* b2r = (const float*)d_in[14];
    const float* W2e = (const float*)d_in[15];
    const float* a2  = (const float*)d_in[16]; const float* c2  = (const float*)d_in[17];
    const float* W3  = (const float*)d_in[18]; const float* b3  = (const float*)d_in[19];
    const float* F1  = (const float*)d_in[20]; const float* bf1 = (const float*)d_in[21];
    const float* F2  = (const float*)d_in[22]; const float* bf2 = (const float*)d_in[23];
    const float* F3  = (const float*)d_in[24]; const float* bf3 = (const float*)d_in[25];

    const int* srcv = ei;        // edge_index[0]
    const int* dstv = ei + EE;   // edge_index[1]

    float* W = (float*)d_ws;
    size_t off = 0;
    int*      hist    = (int*)(W + off); off += NN;
    float*    h1      = W + off; off += (size_t)NN * 100;
    float*    h2      = W + off; off += (size_t)NN * 200;
    int*      rowptr  = (int*)(W + off); off += NN + 4;
    int*      cursor  = (int*)(W + off); off += NN;
    int*      bsum    = (int*)(W + off); off += 256;
    float*    scores  = W + off; off += ET;
    int*      csr_src = (int*)(W + off); off += ET;
    int*      csr_dst = (int*)(W + off); off += ET;
    uint32_t* eaa     = (uint32_t*)(W + off); off += (size_t)ET * 12;
    uint32_t* xl16    = (uint32_t*)(W + off); off += (size_t)NN * 100;
    uint32_t* xr16    = (uint32_t*)(W + off); off += (size_t)NN * 100;
    uint32_t* WeT1    = (uint32_t*)(W + off); off += 26 * 40;
    uint32_t* WeT2    = (uint32_t*)(W + off); off += 50 * 40;
    float*    Wc1     = W + off; off += 16 * 256;
    float*    bc1     = W + off; off += 256;
    float*    Wc2     = W + off; off += 100 * 448;
    float*    bc2     = W + off; off += 448;
    float*    pooled  = W + off; off += (size_t)GG * 200;
    float*    p400    = W + off; off += (size_t)GG * 400;
    float*    y1      = W + off; off += (size_t)GG * 200;
    float*    y2      = W + off; off += (size_t)GG * 100;
    (void)ws_size; (void)n_in; (void)in_sizes; (void)out_size;

    const int B = 256;
    const int NODEB = 12500;   // k_loop2: 50000 waves, 1 node each
    const int PAIRB = 6250;    // k_fin: 25000 waves, 2 nodes each

    // ---- degree histogram + CSR by dst; scatter also packs ea + src/dst ----
    hipMemsetAsync(hist, 0, (size_t)NN * sizeof(int), stream);
    k_hist<<<(EE + B - 1) / B, B, 0, stream>>>(dstv, hist);
    k_scan_a<<<NB, 256, 0, stream>>>(hist, bsum);
    k_scan_b<<<1, 256, 0, stream>>>(bsum, rowptr);
    k_scan_c<<<NB, 256, 0, stream>>>(hist, bsum, rowptr, cursor);
    k_scatter<<<(EE + B - 1) / B, B, 0, stream>>>(srcv, dstv, ea, cursor, csr_src, csr_dst, eaa);
    k_loop2<<<NODEB, B, 0, stream>>>(rowptr, eaa, csr_src, csr_dst);

    // ---- weight prep ----
    k_pack_wet<<<(104 * 10 + B - 1) / B, B, 0, stream>>>(W1e, a1, WeT1, 100, 104);
    k_pack_wet<<<(200 * 10 + B - 1) / B, B, 0, stream>>>(W2e, a2, WeT2, 200, 200);
    k_combine_w<<<(16 * 256 + B - 1) / B, B, 0, stream>>>(W1l, b1l, W1r, b1r, Wc1, bc1, 16, 100, 256);
    k_combine_w<<<(100 * 448 + B - 1) / B, B, 0, stream>>>(W2l, b2l, W2r, b2r, Wc2, bc2, 100, 200, 448);

    // ---- GAT layer 1: 16 -> 100 (RL = 52; pads must be zero for padded score cols) ----
    hipMemsetAsync(xl16, 0, (size_t)NN * 52 * 4, stream);
    hipMemsetAsync(xr16, 0, (size_t)NN * 52 * 4, stream);
    {
        dim3 grid((NN + 63) / 64, 256 / 64);
        k_gemm_dual<16, 256, 100, 52><<<grid, 256, 0, stream>>>(x, Wc1, bc1, xl16, xr16);
    }
    k_score<100, 104><<<(ET / 2 + B - 1) / B, B, 0, stream>>>(csr_src, csr_dst, eaa, WeT1, xl16, xr16, scores);
    k_fin<100, 2, 1><<<PAIRB, B, 0, stream>>>(rowptr, csr_src, scores, xl16, c1, h1);

    // ---- GAT layer 2: 100 -> 200 (RL = 100) ----
    {
        dim3 grid((NN + 63) / 64, 448 / 64);
        k_gemm_dual<100, 448, 200, 100><<<grid, 256, 0, stream>>>(h1, Wc2, bc2, xl16, xr16);
    }
    k_score<200, 200><<<(ET / 2 + B - 1) / B, B, 0, stream>>>(csr_src, csr_dst, eaa, WeT2, xl16, xr16, scores);
    k_fin<200, 4, 0><<<PAIRB, B, 0, stream>>>(rowptr, csr_src, scores, xl16, c2, h2);

    // ---- pool (mean over graph, relu fused) then W3 + FFN ----
    k_pool<<<GG, 256, 0, stream>>>(h2, bat, pooled);
    k_mlp<<<(GG * 400 + B - 1) / B, B, 0, stream>>>(pooled, W3, b3, p400, 200, 400, 0);
    k_mlp<<<(GG * 200 + B - 1) / B, B, 0, stream>>>(p400, F1, bf1, y1, 400, 200, 1);
    k_mlp<<<(GG * 100 + B - 1) / B, B, 0, stream>>>(y1, F2, bf2, y2, 200, 100, 1);
    k_mlp<<<(GG * 100 + B - 1) / B, B, 0, stream>>>(y2, F3, bf3, (float*)d_out, 100, 100, 0);
}

// Round 6
// 1549.081 us; speedup vs baseline: 1.2146x; 1.0657x over previous
//
#include <hip/hip_runtime.h>
#include <cstdint>
#include <climits>
#include <math.h>

#define NN 50000
#define EE 1600000
#define ET (EE + NN)   // real edges + one self-loop per node
#define GG 512
#define NEG_SLOPE 0.2f
#define NB 196          // ceil(NN/256) scan blocks

typedef _Float16 half2v __attribute__((ext_vector_type(2)));

__device__ __forceinline__ uint32_t packh2(float a, float b) {
    union { half2v h; uint32_t u; } c;
    c.h = half2v{(_Float16)a, (_Float16)b};
    return c.u;
}
__device__ __forceinline__ float2 uph(uint32_t u) {
    union { uint32_t u; half2v h; } c;
    c.u = u;
    return make_float2((float)c.h.x, (float)c.h.y);
}
__device__ __forceinline__ uint32_t pkadd(uint32_t a, uint32_t b) {
    union { uint32_t u; half2v h; } x, y, z;
    x.u = a; y.u = b;
    z.h = x.h + y.h;    // v_pk_add_f16
    return z.u;
}
__device__ __forceinline__ float fdot2u(uint32_t a, uint32_t b, float c) {
    union { uint32_t u; half2v h; } ua, ub;
    ua.u = a; ub.u = b;
    return __builtin_amdgcn_fdot2(ua.h, ub.h, c, false);
}
__device__ __forceinline__ float rlanef(float v, int l) {
    return __int_as_float(__builtin_amdgcn_readlane(__float_as_int(v), l));
}

// ---------- degree histogram ----------
__global__ void k_hist(const int* __restrict__ dst, int* __restrict__ hist) {
    int e = blockIdx.x * blockDim.x + threadIdx.x;
    if (e < EE) atomicAdd(&hist[dst[e]], 1);
}

// ---------- CSR build ----------
__global__ void k_scan_a(const int* __restrict__ hist, int* __restrict__ bsum) {
    __shared__ int tmp[256];
    int i = blockIdx.x * 256 + threadIdx.x;
    tmp[threadIdx.x] = (i < NN) ? hist[i] : 0;
    __syncthreads();
    for (int d = 128; d; d >>= 1) {
        if (threadIdx.x < d) tmp[threadIdx.x] += tmp[threadIdx.x + d];
        __syncthreads();
    }
    if (threadIdx.x == 0) bsum[blockIdx.x] = tmp[0];
}

__global__ void k_scan_b(int* __restrict__ bsum, int* __restrict__ rowptr) {
    __shared__ int tmp[256];
    int t = threadIdx.x;
    int v = (t < NB) ? bsum[t] : 0;
    tmp[t] = v;
    __syncthreads();
    for (int d = 1; d < 256; d <<= 1) {
        int u = (t >= d) ? tmp[t - d] : 0;
        __syncthreads();
        tmp[t] += u;
        __syncthreads();
    }
    if (t < NB) bsum[t] = tmp[t] - v;        // exclusive
    if (t == 255) rowptr[NN] = tmp[255];     // total == EE
}

// rowptr + cursor init fused
__global__ void k_scan_c(const int* __restrict__ hist, const int* __restrict__ bsum,
                         int* __restrict__ rowptr, int* __restrict__ cursor) {
    __shared__ int tmp[256];
    int i = blockIdx.x * 256 + threadIdx.x;
    int v = (i < NN) ? hist[i] : 0;
    tmp[threadIdx.x] = v;
    __syncthreads();
    for (int d = 1; d < 256; d <<= 1) {
        int t = (threadIdx.x >= d) ? tmp[threadIdx.x - d] : 0;
        __syncthreads();
        tmp[threadIdx.x] += t;
        __syncthreads();
    }
    if (i < NN) {
        int rp = tmp[threadIdx.x] - v + bsum[blockIdx.x];
        rowptr[i] = rp;
        cursor[i] = rp;
    }
}

// ---------- scatter + csr_src + fp16 AoS ea pack, one pass ----------
__global__ void k_scatter(const int* __restrict__ srcv, const int* __restrict__ dstv,
                          const float* __restrict__ ea, int* __restrict__ cursor,
                          int* __restrict__ csr_src, uint32_t* __restrict__ eaa) {
    int e = blockIdx.x * blockDim.x + threadIdx.x;
    if (e >= EE) return;
    int d = dstv[e];
    int p = atomicAdd(&cursor[d], 1);
    csr_src[p] = srcv[e];
    const float* r = ea + (size_t)e * 18;
    uint32_t o[12];
#pragma unroll
    for (int kk = 0; kk < 9; kk++) {
        float2 q = *(const float2*)(r + 2 * kk);
        o[kk] = packh2(q.x, q.y);
    }
    o[9] = o[10] = o[11] = 0;
    uint4* dst = (uint4*)(eaa + (size_t)p * 12);
    dst[0] = *(uint4*)&o[0];
    dst[1] = *(uint4*)&o[4];
    dst[2] = *(uint4*)&o[8];
}

// ---------- self-loop edge attr = mean of incoming ea; append virtual entries ----------
__global__ void __launch_bounds__(256)
k_loop2(const int* __restrict__ rowptr, uint32_t* __restrict__ eaa) {
    const int lane = threadIdx.x & 63;
    int wid = blockIdx.x * (blockDim.x >> 6) + (threadIdx.x >> 6);
    int nw = gridDim.x * (blockDim.x >> 6);

    for (int i = wid; i < NN; i += nw) {
        int beg = __builtin_amdgcn_readfirstlane(rowptr[i]);
        int end = __builtin_amdgcn_readfirstlane(rowptr[i + 1]);
        float s[18];
#pragma unroll
        for (int j = 0; j < 18; j++) s[j] = 0.f;
        for (int cs = beg; cs < end; cs += 64) {
            int cnt = end - cs; if (cnt > 64) cnt = 64;
            if (lane < cnt) {
                const uint32_t* pe = eaa + (size_t)(cs + lane) * 12;
                uint4 a = *(const uint4*)pe;
                uint4 b = *(const uint4*)(pe + 4);
                uint32_t c = pe[8];
                uint32_t w[9] = {a.x, a.y, a.z, a.w, b.x, b.y, b.z, b.w, c};
#pragma unroll
                for (int kk = 0; kk < 9; kk++) {
                    float2 q = uph(w[kk]);
                    s[2 * kk] += q.x; s[2 * kk + 1] += q.y;
                }
            }
        }
#pragma unroll
        for (int j = 0; j < 18; j++) {
#pragma unroll
            for (int off = 32; off; off >>= 1) s[j] += __shfl_xor(s[j], off, 64);
        }
        if (lane == 0) {
            int deg = end - beg;
            float rd = (deg > 0) ? 1.0f / (float)deg : 0.0f;
            uint32_t o[12];
#pragma unroll
            for (int kk = 0; kk < 9; kk++) o[kk] = packh2(s[2 * kk] * rd, s[2 * kk + 1] * rd);
            o[9] = o[10] = o[11] = 0;
            uint4* dst = (uint4*)(eaa + (size_t)(EE + i) * 12);
            dst[0] = *(uint4*)&o[0];
            dst[1] = *(uint4*)&o[4];
            dst[2] = *(uint4*)&o[8];
        }
    }
}

// ---------- pack WeT (zero-padded to CP cols): per col: 9 fp16-pair dwords + att ----------
__global__ void k_pack_wet(const float* __restrict__ We, const float* __restrict__ att,
                           uint32_t* __restrict__ WeT, int C, int CP) {
    int t = blockIdx.x * blockDim.x + threadIdx.x;
    if (t >= CP * 10) return;
    int c = t / 10, kk = t - c * 10;
    int g = c >> 2, j = c & 3;
    uint32_t v = 0;
    if (c < C) {
        if (kk < 9) v = packh2(We[(2 * kk) * C + c], We[(2 * kk + 1) * C + c]);
        else v = __float_as_uint(att[c]);
    }
    WeT[g * 40 + j * 10 + kk] = v;
}

// ---------- combine Wl|Wr into padded Wc [K x NP], biases into bc [NP] ----------
__global__ void k_combine_w(const float* __restrict__ Wl, const float* __restrict__ bl,
                            const float* __restrict__ Wr, const float* __restrict__ br,
                            float* __restrict__ Wc, float* __restrict__ bc,
                            int K, int C, int NP) {
    int t = blockIdx.x * blockDim.x + threadIdx.x;
    if (t < K * NP) {
        int k = t / NP, n = t - k * NP;
        float v = 0.0f;
        if (n < C) v = Wl[k * C + n];
        else if (n < 2 * C) v = Wr[k * C + n - C];
        Wc[t] = v;
    }
    if (t < NP) {
        float v = 0.0f;
        if (t < C) v = bl[t];
        else if (t < 2 * C) v = br[t - C];
        bc[t] = v;
    }
}

// ---------- tiled dual GEMM -> xl16/xr16 (packed fp16, padded pitch RL) ----------
template <int KK, int NP, int C, int RL>
__global__ void __launch_bounds__(256)
k_gemm_dual(const float* __restrict__ A, const float* __restrict__ Wc,
            const float* __restrict__ bc,
            uint32_t* __restrict__ xl16, uint32_t* __restrict__ xr16) {
    constexpr int BM = 64, BN = 64, BK = 16;
    __shared__ float As[BK][BM];
    __shared__ float Ws[BK][BN];
    const int tidx = threadIdx.x;
    const int tx = tidx & 15;
    const int ty = tidx >> 4;
    const int m0 = blockIdx.x * BM;
    const int n0 = blockIdx.y * BN;

    float acc[4][4];
#pragma unroll
    for (int i2 = 0; i2 < 4; i2++)
#pragma unroll
        for (int j2 = 0; j2 < 4; j2++) acc[i2][j2] = 0.0f;

    for (int k0 = 0; k0 < KK; k0 += BK) {
        {
            int m = tidx >> 2;
            int kq = (tidx & 3) * 4;
            float4 v = make_float4(0.f, 0.f, 0.f, 0.f);
            if (m0 + m < NN && k0 + kq < KK)
                v = *(const float4*)(A + (size_t)(m0 + m) * KK + k0 + kq);
            As[kq + 0][m] = v.x; As[kq + 1][m] = v.y;
            As[kq + 2][m] = v.z; As[kq + 3][m] = v.w;
        }
        {
            int k = tidx >> 4;
            int nq = (tidx & 15) * 4;
            float4 v = make_float4(0.f, 0.f, 0.f, 0.f);
            if (k0 + k < KK)
                v = *(const float4*)(Wc + (size_t)(k0 + k) * NP + n0 + nq);
            *(float4*)&Ws[k][nq] = v;
        }
        __syncthreads();
#pragma unroll
        for (int k = 0; k < BK; k++) {
            float a[4], b[4];
            *(float4*)a = *(const float4*)&As[k][ty * 4];
            *(float4*)b = *(const float4*)&Ws[k][tx * 4];
#pragma unroll
            for (int i2 = 0; i2 < 4; i2++)
#pragma unroll
                for (int j2 = 0; j2 < 4; j2++) acc[i2][j2] += a[i2] * b[j2];
        }
        __syncthreads();
    }

    const int n = n0 + tx * 4;
    float4 bcv = *(const float4*)(bc + n);
#pragma unroll
    for (int i2 = 0; i2 < 4; i2++) {
        int m = m0 + ty * 4 + i2;
        if (m >= NN) continue;
        float4 o = make_float4(acc[i2][0] + bcv.x, acc[i2][1] + bcv.y,
                               acc[i2][2] + bcv.z, acc[i2][3] + bcv.w);
        uint2 p;
        p.x = packh2(o.x, o.y);
        p.y = packh2(o.z, o.w);
        if (n < C)          *(uint2*)(xl16 + (size_t)m * RL + n / 2) = p;
        else if (n < 2 * C) *(uint2*)(xr16 + (size_t)m * RL + (n - C) / 2) = p;
    }
}

// ---------- fused GAT: wave per node, LDS row cache, per-chunk online softmax ----------
// Lane = edge within 64-edge chunk. Virtual self-loop at position `end` of [beg, end+1).
template <int C, int VEC, int RELU>
__global__ void __launch_bounds__(64)
k_gat(const int* __restrict__ rowptr, const int* __restrict__ csr_src,
      const uint32_t* __restrict__ eaa, const uint32_t* __restrict__ WeT,
      const uint32_t* __restrict__ xl16, const uint32_t* __restrict__ xr16,
      const float* __restrict__ bias, float* __restrict__ out) {
    constexpr int RL = ((C / 2) + 3) & ~3;   // global row pitch (dwords): 52 / 100
    constexpr int LP = RL + 1;               // LDS pitch, odd -> conflict-free b32
    constexpr int NQ = RL / 4;               // uint4 per row: 13 / 25
    constexpr int NL = C / VEC;              // active agg lanes: 50
    constexpr int DW = VEC / 2;              // dwords per agg lane: 1 / 2
    __shared__ uint32_t s_rows[64 * LP];
    __shared__ uint32_t s_xr[RL];
    const int lane = threadIdx.x;

    for (int i = blockIdx.x; i < NN; i += gridDim.x) {
        int beg = __builtin_amdgcn_readfirstlane(rowptr[i]);
        int end = __builtin_amdgcn_readfirstlane(rowptr[i + 1]);
        int endp = end + 1;   // + virtual self edge

        // xr[dst] row -> LDS once per node (coalesced)
        for (int j = lane; j < RL; j += 64) s_xr[j] = xr16[(size_t)i * RL + j];

        float m = -INFINITY, z = 0.0f;
        float acc[VEC];
#pragma unroll
        for (int j = 0; j < VEC; j++) acc[j] = 0.0f;

        for (int cs = beg; cs < endp; cs += 64) {
            int cnt = endp - cs; if (cnt > 64) cnt = 64;
            int pos = cs + lane;
            bool ae = pos < endp;

            // ---- gather row + ea into regs (13/25 + 3 independent loads/lane) ----
            uint4 st[NQ];
            uint32_t ear[9];
            if (ae) {
                int sx = (pos < end) ? csr_src[pos] : i;
                size_t eidx = (pos < end) ? (size_t)pos : (size_t)(EE + i);
                const uint4* pr = (const uint4*)(xl16 + (size_t)sx * RL);
#pragma unroll
                for (int q = 0; q < NQ; q++) st[q] = pr[q];
                const uint32_t* pe = eaa + eidx * 12;
                uint4 e0 = *(const uint4*)pe;
                uint4 e1 = *(const uint4*)(pe + 4);
                ear[0] = e0.x; ear[1] = e0.y; ear[2] = e0.z; ear[3] = e0.w;
                ear[4] = e1.x; ear[5] = e1.y; ear[6] = e1.z; ear[7] = e1.w;
                ear[8] = pe[8];
            }
            __builtin_amdgcn_sched_barrier(0);   // pin: all loads issued first

            // ---- rows -> LDS (conflict-free: odd pitch) ----
            if (ae) {
#pragma unroll
                for (int q = 0; q < NQ; q++) {
                    s_rows[lane * LP + 4 * q + 0] = st[q].x;
                    s_rows[lane * LP + 4 * q + 1] = st[q].y;
                    s_rows[lane * LP + 4 * q + 2] = st[q].z;
                    s_rows[lane * LP + 4 * q + 3] = st[q].w;
                }
            }

            // ---- in-lane score over own row (from LDS) ----
            float s = -INFINITY;
            if (ae) {
                float sc = 0.0f;
#pragma unroll 2
                for (int d = 0; d < RL; d++) {
                    uint32_t u = pkadd(s_rows[lane * LP + d], s_xr[d]);
                    float2 f = uph(u);
                    const uint32_t* wg0 = WeT + (d >> 1) * 40 + (d & 1) * 20;  // uniform -> scalar
                    float w0 = 0.0f, w1 = 0.0f;
#pragma unroll
                    for (int kk = 0; kk < 9; kk++) {
                        w0 = fdot2u(ear[kk], wg0[kk], w0);
                        w1 = fdot2u(ear[kk], wg0[10 + kk], w1);
                    }
                    float u0 = f.x + w0, u1 = f.y + w1;
                    float h0 = fmaxf(u0, NEG_SLOPE * u0);
                    float h1v = fmaxf(u1, NEG_SLOPE * u1);
                    sc = fmaf(__uint_as_float(wg0[9]), h0, sc);
                    sc = fmaf(__uint_as_float(wg0[19]), h1v, sc);
                }
                s = sc;
            }

            // ---- per-chunk online softmax ----
            float pmax = s;
#pragma unroll
            for (int off = 32; off; off >>= 1) pmax = fmaxf(pmax, __shfl_xor(pmax, off, 64));
            float mn = fmaxf(m, pmax);
            float sca = __expf(m - mn);     // m=-inf first chunk -> 0
            float pe = __expf(s - mn);      // inactive lanes: exp(-inf)=0
            float zc = pe;
#pragma unroll
            for (int off = 32; off; off >>= 1) zc += __shfl_xor(zc, off, 64);
            z = z * sca + zc;
            m = mn;
#pragma unroll
            for (int j = 0; j < VEC; j++) acc[j] *= sca;

            // ---- aggregate from LDS rows (lane = column block) ----
            if (lane < NL) {
                for (int e = 0; e < cnt; e++) {
                    float a = rlanef(pe, e);
#pragma unroll
                    for (int q = 0; q < DW; q++) {
                        float2 f = uph(s_rows[e * LP + lane * DW + q]);
                        acc[2 * q] = fmaf(a, f.x, acc[2 * q]);
                        acc[2 * q + 1] = fmaf(a, f.y, acc[2 * q + 1]);
                    }
                }
            }
        }

        if (lane < NL) {
            float rz = 1.0f / z;
            float o[VEC];
#pragma unroll
            for (int j = 0; j < VEC; j++) {
                o[j] = acc[j] * rz + bias[lane * VEC + j];
                if (RELU) o[j] = fmaxf(o[j], 0.0f);
            }
            if constexpr (VEC == 4) {
                *(float4*)(out + (size_t)i * C + lane * 4) = make_float4(o[0], o[1], o[2], o[3]);
            } else {
                *(float2*)(out + (size_t)i * C + lane * 2) = make_float2(o[0], o[1]);
            }
        }
    }
}

// ---------- mean pooling per graph (batch_ids sorted); relu folded in ----------
__global__ void k_pool(const float* __restrict__ h, const int* __restrict__ batch,
                       float* __restrict__ pooled) {
    int g = blockIdx.x;
    int lo = 0, hi = NN;
    while (lo < hi) { int mid = (lo + hi) >> 1; if (batch[mid] < g) lo = mid + 1; else hi = mid; }
    int start = lo;
    lo = start; hi = NN;
    while (lo < hi) { int mid = (lo + hi) >> 1; if (batch[mid] < g + 1) lo = mid + 1; else hi = mid; }
    int end = lo;
    float cnt = (float)(end - start);
    int c = threadIdx.x;
    if (c < 200) {
        float acc = 0.0f;
        for (int i = start; i < end; i++) acc += fmaxf(h[(size_t)i * 200 + c], 0.0f);
        pooled[g * 200 + c] = acc / fmaxf(cnt, 1.0f);
    }
}

// ---------- small dense layers on [G, *] ----------
__global__ void k_mlp(const float* __restrict__ X, const float* __restrict__ W,
                      const float* __restrict__ b, float* __restrict__ Y,
                      int Cin, int Cout, int do_relu) {
    int t = blockIdx.x * blockDim.x + threadIdx.x;
    if (t >= GG * Cout) return;
    int g = t / Cout, j = t - g * Cout;
    const float* xrow = X + (size_t)g * Cin;
    float acc = b[j];
    for (int k = 0; k < Cin; k++) acc += xrow[k] * W[k * Cout + j];
    if (do_relu) acc = fmaxf(acc, 0.0f);
    Y[t] = acc;
}

extern "C" void kernel_launch(void* const* d_in, const int* in_sizes, int n_in,
                              void* d_out, int out_size, void* d_ws, size_t ws_size,
                              hipStream_t stream) {
    const float* x   = (const float*)d_in[0];
    const int*   ei  = (const int*)d_in[1];
    const float* ea  = (const float*)d_in[2];
    const int*   bat = (const int*)d_in[3];
    const float* W1l = (const float*)d_in[4];  const float* b1l = (const float*)d_in[5];
    const float* W1r = (const float*)d_in[6];  const float* b1r = (const float*)d_in[7];
    const float* W1e = (const float*)d_in[8];
    const float* a1  = (const float*)d_in[9];  const float* c1  = (const float*)d_in[10];
    const float* W2l = (const float*)d_in[11]; const float* b2l = (const float*)d_in[12];
    const float* W2r = (const float*)d_in[13]; const float* b2r = (const float*)d_in[14];
    const float* W2e = (const float*)d_in[15];
    const float* a2  = (const float*)d_in[16]; const float* c2  = (const float*)d_in[17];
    const float* W3  = (const float*)d_in[18]; const float* b3  = (const float*)d_in[19];
    const float* F1  = (const float*)d_in[20]; const float* bf1 = (const float*)d_in[21];
    const float* F2  = (const float*)d_in[22]; const float* bf2 = (const float*)d_in[23];
    const float* F3  = (const float*)d_in[24]; const float* bf3 = (const float*)d_in[25];

    const int* srcv = ei;        // edge_index[0]
    const int* dstv = ei + EE;   // edge_index[1]

    float* W = (float*)d_ws;
    size_t off = 0;
    int*      hist    = (int*)(W + off); off += NN;
    float*    h1      = W + off; off += (size_t)NN * 100;
    float*    h2      = W + off; off += (size_t)NN * 200;
    int*      rowptr  = (int*)(W + off); off += NN + 4;
    int*      cursor  = (int*)(W + off); off += NN;
    int*      bsum    = (int*)(W + off); off += 256;
    int*      csr_src = (int*)(W + off); off += ET;
    uint32_t* eaa     = (uint32_t*)(W + off); off += (size_t)ET * 12;
    uint32_t* xl16    = (uint32_t*)(W + off); off += (size_t)NN * 100;
    uint32_t* xr16    = (uint32_t*)(W + off); off += (size_t)NN * 100;
    uint32_t* WeT1    = (uint32_t*)(W + off); off += 26 * 40;
    uint32_t* WeT2    = (uint32_t*)(W + off); off += 50 * 40;
    float*    Wc1     = W + off; off += 16 * 256;
    float*    bc1     = W + off; off += 256;
    float*    Wc2     = W + off; off += 100 * 448;
    float*    bc2     = W + off; off += 448;
    float*    pooled  = W + off; off += (size_t)GG * 200;
    float*    p400    = W + off; off += (size_t)GG * 400;
    float*    y1      = W + off; off += (size_t)GG * 200;
    float*    y2      = W + off; off += (size_t)GG * 100;
    (void)ws_size; (void)n_in; (void)in_sizes; (void)out_size;

    const int B = 256;
    const int NODEB = 12500;   // k_loop2: 50000 waves, 1 node each

    // ---- degree histogram + CSR by dst; scatter also packs ea + src ----
    hipMemsetAsync(hist, 0, (size_t)NN * sizeof(int), stream);
    k_hist<<<(EE + B - 1) / B, B, 0, stream>>>(dstv, hist);
    k_scan_a<<<NB, 256, 0, stream>>>(hist, bsum);
    k_scan_b<<<1, 256, 0, stream>>>(bsum, rowptr);
    k_scan_c<<<NB, 256, 0, stream>>>(hist, bsum, rowptr, cursor);
    k_scatter<<<(EE + B - 1) / B, B, 0, stream>>>(srcv, dstv, ea, cursor, csr_src, eaa);
    k_loop2<<<NODEB, B, 0, stream>>>(rowptr, eaa);

    // ---- weight prep ----
    k_pack_wet<<<(104 * 10 + B - 1) / B, B, 0, stream>>>(W1e, a1, WeT1, 100, 104);
    k_pack_wet<<<(200 * 10 + B - 1) / B, B, 0, stream>>>(W2e, a2, WeT2, 200, 200);
    k_combine_w<<<(16 * 256 + B - 1) / B, B, 0, stream>>>(W1l, b1l, W1r, b1r, Wc1, bc1, 16, 100, 256);
    k_combine_w<<<(100 * 448 + B - 1) / B, B, 0, stream>>>(W2l, b2l, W2r, b2r, Wc2, bc2, 100, 200, 448);

    // ---- GAT layer 1: 16 -> 100 (RL = 52; pad dwords must be zero) ----
    hipMemsetAsync(xl16, 0, (size_t)NN * 52 * 4, stream);
    hipMemsetAsync(xr16, 0, (size_t)NN * 52 * 4, stream);
    {
        dim3 grid((NN + 63) / 64, 256 / 64);
        k_gemm_dual<16, 256, 100, 52><<<grid, 256, 0, stream>>>(x, Wc1, bc1, xl16, xr16);
    }
    k_gat<100, 2, 1><<<NN, 64, 0, stream>>>(rowptr, csr_src, eaa, WeT1, xl16, xr16, c1, h1);

    // ---- GAT layer 2: 100 -> 200 (RL = 100) ----
    {
        dim3 grid((NN + 63) / 64, 448 / 64);
        k_gemm_dual<100, 448, 200, 100><<<grid, 256, 0, stream>>>(h1, Wc2, bc2, xl16, xr16);
    }
    k_gat<200, 4, 0><<<NN, 64, 0, stream>>>(rowptr, csr_src, eaa, WeT2, xl16, xr16, c2, h2);

    // ---- pool (mean over graph, relu fused) then W3 + FFN ----
    k_pool<<<GG, 256, 0, stream>>>(h2, bat, pooled);
    k_mlp<<<(GG * 400 + B - 1) / B, B, 0, stream>>>(pooled, W3, b3, p400, 200, 400, 0);
    k_mlp<<<(GG * 200 + B - 1) / B, B, 0, stream>>>(p400, F1, bf1, y1, 400, 200, 1);
    k_mlp<<<(GG * 100 + B - 1) / B, B, 0, stream>>>(y1, F2, bf2, y2, 200, 100, 1);
    k_mlp<<<(GG * 100 + B - 1) / B, B, 0, stream>>>(y2, F3, bf3, (float*)d_out, 100, 100, 0);
}